// Round 11
// baseline (449.980 us; speedup 1.0000x reference)
//
#include <hip/hip_runtime.h>
#include <stdint.h>

typedef __attribute__((ext_vector_type(8))) short bf16x8;
typedef __attribute__((ext_vector_type(4))) float f32x4;
typedef __attribute__((ext_vector_type(4))) unsigned short u16x4;

#define SEQ 4096

__device__ __forceinline__ float bf2f(unsigned short u) {
  union { unsigned int i; float f; } v; v.i = ((unsigned int)u) << 16; return v.f;
}
__device__ __forceinline__ unsigned short f2bf(float f) {
  union { float f; unsigned int i; } v; v.f = f;
  unsigned int u = v.i;
  u = u + 0x7FFFu + ((u >> 16) & 1u);
  return (unsigned short)(u >> 16);
}
__device__ __forceinline__ unsigned pack2bf(float a, float b) {
  return (unsigned)f2bf(a) | ((unsigned)f2bf(b) << 16);
}
__device__ __forceinline__ float sigm(float x) { return 1.0f / (1.0f + __expf(-x)); }

// ---------------- conversion kernels ----------------

// batched transpose fp32 [K][N] -> bf16 [N][K]; z selects matrix
__global__ void tconvb_kernel(const float* __restrict__ s0, const float* __restrict__ s1,
                              const float* __restrict__ s2, const float* __restrict__ s3,
                              const float* __restrict__ s4, unsigned short* __restrict__ WT4,
                              unsigned short* __restrict__ WTout) {
  __shared__ float t[32][33];
  int z = blockIdx.z;
  const float* src; unsigned short* dst; int K, k0;
  if (z < 4) {
    src = (z == 0) ? s0 : (z == 1) ? s1 : (z == 2) ? s2 : s3;
    dst = WT4 + (size_t)z * 1048576; K = 1024; k0 = blockIdx.y * 32;
  } else {
    src = s4; dst = WTout; K = 2048; k0 = blockIdx.y * 32 + (z - 4) * 1024;
  }
  int n0 = blockIdx.x * 32;
  int tx = threadIdx.x & 31, ty = threadIdx.x >> 5;
#pragma unroll
  for (int i = 0; i < 32; i += 8)
    t[ty + i][tx] = src[(size_t)(k0 + ty + i) * 1024 + n0 + tx];
  __syncthreads();
#pragma unroll
  for (int i = 0; i < 32; i += 8)
    dst[(size_t)(n0 + ty + i) * K + k0 + tx] = f2bf(t[tx][ty + i]);
}

__global__ void concat_bias_kernel(const float* b0, const float* b1, const float* b2,
                                   const float* b3, float* b4) {
  int i = blockIdx.x * 256 + threadIdx.x;  // 0..4095
  const float* p = (i < 1024) ? b0 : (i < 2048) ? b1 : (i < 3072) ? b2 : b3;
  b4[i] = p[i & 1023];
}

// ---------------- shared epilogue ----------------
template <int MODE>
__device__ __forceinline__ void store_frag(const f32x4& v, const float* bias, void* Cout,
                                           int col, int rb) {
  float bcol = bias[col];
  if (MODE == 0) {
    unsigned short* ACTp = (unsigned short*)Cout;
    bool isz = ((col >> 10) & 1) == 0;  // groups 0,2 are z-gates
#pragma unroll
    for (int r = 0; r < 4; ++r) {
      float x = v[r] + bcol;
      float res;
      if (isz) res = sigm(-x);                       // a = 1 - z
      else res = (x >= 0.f) ? (x + 0.5f) : sigm(x);  // g(x)
      ACTp[(size_t)(rb + r) * 4096 + col] = f2bf(res);
    }
  } else {
    float* Op = (float*)Cout;
#pragma unroll
    for (int r = 0; r < 4; ++r) Op[(size_t)(rb + r) * 1024 + col] = v[r] + bcol;
  }
}

// inline-asm ds_read_b128 (pinned; not sinkable/splittable)
#define DSR(D, A, OFFSTR) \
  asm volatile("ds_read_b128 %0, %1 offset:" OFFSTR : "=&v"(D) : "v"(A))

#define GLL(SRC, DIDX)                                                                  \
  __builtin_amdgcn_global_load_lds((const __attribute__((address_space(1))) void*)(SRC), \
                                   (__attribute__((address_space(3))) void*)&lds[DIDX], \
                                   16, 0, 0)

// ---------------- 256x256 GEMM1, reg-staged, A = fp32 x with fused bf16 convert ----
// Staging: A loads fp32 float4x2 per 16B-bf16 chunk, convert in reg; B loads bf16.
// Loads issued BEFORE the MFMA cluster, ds_writes after (T14). One barrier/iter.
__global__ __launch_bounds__(512, 2) void gemm256x_kernel(
    const float* __restrict__ Xf, const unsigned short* __restrict__ BT,
    const float* __restrict__ bias, void* __restrict__ Cout, int K, int NT) {
  // LDS bytes: A buf b at b*16384 (256 rows x 64B); B buf b at 32768 + b*16384.
  // swizzle kbyte ^= ((row>>1)&3)<<4
  __shared__ unsigned short lds[32768];  // 64 KB

  const int tid = threadIdx.x;
  const int lane = tid & 63;
  const int wv = tid >> 6;
  const int wm = wv >> 2;
  const int wn = wv & 3;
  const int lo = lane & 15, hi = lane >> 4;

  const int nwg = gridDim.x;
  const int bid = blockIdx.x;
  const int cpx = nwg >> 3;
  const int sw = (bid & 7) * cpx + (bid >> 3);
  const int mt = sw / NT, nt = sw - mt * NT;
  const int m0 = mt << 8, n0 = nt << 8;

  // per-thread staging addresses: thread owns 16B(bf16) = 8 elems per region.
  const int srow = tid >> 2;
  const int skb = (((tid & 3) ^ ((tid >> 3) & 3)) << 4);  // bf16 byte offset
  const int sel = skb >> 1;                               // element offset (mult of 8)
  const float* pA0 = Xf + (size_t)(m0 + srow) * K + sel;
  const float* pA1 = pA0 + (size_t)128 * K;
  const unsigned short* pB0 = BT + (size_t)(n0 + srow) * K + sel;
  const unsigned short* pB1 = pB0 + (size_t)128 * K;
  char* const ldsB = (char*)lds;

  float4 fA0a, fA0b, fA1a, fA1b;
  uint4 rB0, rB1;
#define LOADR(KT)                                  \
  do {                                             \
    const int ko_ = (KT) << 5;                     \
    fA0a = *(const float4*)(pA0 + ko_);            \
    fA0b = *(const float4*)(pA0 + ko_ + 4);        \
    fA1a = *(const float4*)(pA1 + ko_);            \
    fA1b = *(const float4*)(pA1 + ko_ + 4);        \
    rB0 = *(const uint4*)(pB0 + ko_);              \
    rB1 = *(const uint4*)(pB1 + ko_);              \
  } while (0)
#define WRITR(BUF)                                                        \
  do {                                                                    \
    const int bo_ = (BUF) * 16384 + tid * 16;                             \
    uint4 wA0, wA1;                                                       \
    wA0.x = pack2bf(fA0a.x, fA0a.y); wA0.y = pack2bf(fA0a.z, fA0a.w);     \
    wA0.z = pack2bf(fA0b.x, fA0b.y); wA0.w = pack2bf(fA0b.z, fA0b.w);     \
    wA1.x = pack2bf(fA1a.x, fA1a.y); wA1.y = pack2bf(fA1a.z, fA1a.w);     \
    wA1.z = pack2bf(fA1b.x, fA1b.y); wA1.w = pack2bf(fA1b.z, fA1b.w);     \
    *(uint4*)(ldsB + bo_) = wA0;                                          \
    *(uint4*)(ldsB + bo_ + 8192) = wA1;                                   \
    *(uint4*)(ldsB + 32768 + bo_) = rB0;                                  \
    *(uint4*)(ldsB + 32768 + bo_ + 8192) = rB1;                           \
  } while (0)

  f32x4 acc[8][4];
#pragma unroll
  for (int i = 0; i < 8; ++i)
#pragma unroll
    for (int j = 0; j < 4; ++j) acc[i][j] = (f32x4){0.f, 0.f, 0.f, 0.f};

  const int swz = ((lo >> 1) & 3) << 4;
  const int kof = ((hi << 4) ^ swz) >> 1;
  const unsigned ldsBase = (unsigned)(unsigned long long)&lds[0];
  const unsigned aByte = ldsBase + (unsigned)((((wm * 128 + lo) * 32) + kof) << 1);
  const unsigned bByte = ldsBase + 32768u + (unsigned)((((wn * 64 + lo) * 32) + kof) << 1);

  const int nT = K >> 5;
  LOADR(0);
  WRITR(0);
  __syncthreads();
  for (int kt = 0; kt < nT; ++kt) {
    const int buf = kt & 1;
    if (kt + 1 < nT) LOADR(kt + 1);  // global loads in flight across the MFMA cluster

    const unsigned aA = aByte + (unsigned)(buf << 14);
    const unsigned bA = bByte + (unsigned)(buf << 14);
    bf16x8 af0, af1, af2, af3, af4, af5, af6, af7, bf0, bf1, bf2, bf3;
    DSR(af0, aA, "0");    DSR(af1, aA, "1024");
    DSR(af2, aA, "2048"); DSR(af3, aA, "3072");
    DSR(af4, aA, "4096"); DSR(af5, aA, "5120");
    DSR(af6, aA, "6144"); DSR(af7, aA, "7168");
    DSR(bf0, bA, "0");    DSR(bf1, bA, "1024");
    DSR(bf2, bA, "2048"); DSR(bf3, bA, "3072");
    asm volatile("s_waitcnt lgkmcnt(0)" ::: "memory");
    __builtin_amdgcn_sched_barrier(0);  // rule #18
    __builtin_amdgcn_s_setprio(1);
#define MM(MI, NI) \
    acc[MI][NI] = __builtin_amdgcn_mfma_f32_16x16x32_bf16(af##MI, bf##NI, acc[MI][NI], 0, 0, 0)
    MM(0, 0); MM(0, 1); MM(0, 2); MM(0, 3);
    MM(1, 0); MM(1, 1); MM(1, 2); MM(1, 3);
    MM(2, 0); MM(2, 1); MM(2, 2); MM(2, 3);
    MM(3, 0); MM(3, 1); MM(3, 2); MM(3, 3);
    MM(4, 0); MM(4, 1); MM(4, 2); MM(4, 3);
    MM(5, 0); MM(5, 1); MM(5, 2); MM(5, 3);
    MM(6, 0); MM(6, 1); MM(6, 2); MM(6, 3);
    MM(7, 0); MM(7, 1); MM(7, 2); MM(7, 3);
#undef MM
    __builtin_amdgcn_s_setprio(0);
    __builtin_amdgcn_sched_barrier(0);  // cvt+ds_writes stay below the cluster
    if (kt + 1 < nT) WRITR(buf ^ 1);    // vmcnt wait lands here, post-MFMA
    __syncthreads();
  }
#undef LOADR
#undef WRITR

#pragma unroll
  for (int mi = 0; mi < 8; ++mi)
#pragma unroll
    for (int ni = 0; ni < 4; ++ni)
      store_frag<0>(acc[mi][ni], bias, Cout,
                    n0 + wn * 64 + ni * 16 + lo,
                    m0 + wm * 128 + mi * 16 + hi * 4);
}

// ---------------- 128x256 GEMM (GEMM2), GLL staging ----------
template <int MODE>
__global__ __launch_bounds__(512, 2) void gemm128_kernel(
    const unsigned short* __restrict__ A, const unsigned short* __restrict__ BT,
    const float* __restrict__ bias, void* __restrict__ Cout, int K, int NT) {
  __shared__ unsigned short lds[24576];  // 48 KB

  const int tid = threadIdx.x;
  const int lane = tid & 63;
  const int wv = tid >> 6;
  const int wm = wv >> 2;
  const int wn = wv & 3;
  const int lo = lane & 15, hi = lane >> 4;

  const int nwg = gridDim.x;
  const int bid = blockIdx.x;
  const int cpx = nwg >> 3;
  const int sw = (bid & 7) * cpx + (bid >> 3);
  const int mt = sw / NT, nt = sw - mt * NT;
  const int m0 = mt << 7, n0 = nt << 8;

  const int srow = tid >> 2;
  const int skb = (((tid & 3) ^ ((tid >> 3) & 3)) << 4);
  const unsigned short* pA0 = A + (size_t)(m0 + srow) * K + (skb >> 1);
  const unsigned short* pB0 = BT + (size_t)(n0 + srow) * K + (skb >> 1);
  const unsigned short* pB1 = pB0 + (size_t)128 * K;
  const int dstBase = wv << 9;

#define STAGE(KT, BUF)                                    \
  do {                                                    \
    const int ko_ = (KT) << 5;                            \
    GLL(pA0 + ko_, (BUF) * 4096 + dstBase);               \
    GLL(pB0 + ko_, 8192 + (BUF) * 8192 + dstBase);        \
    GLL(pB1 + ko_, 8192 + (BUF) * 8192 + 4096 + dstBase); \
  } while (0)

  f32x4 acc[4][4];
#pragma unroll
  for (int i = 0; i < 4; ++i)
#pragma unroll
    for (int j = 0; j < 4; ++j) acc[i][j] = (f32x4){0.f, 0.f, 0.f, 0.f};

  const int swz = ((lo >> 1) & 3) << 4;
  const int kof = ((hi << 4) ^ swz) >> 1;
  const unsigned ldsBase = (unsigned)(unsigned long long)&lds[0];
  const unsigned aByte = ldsBase + (unsigned)((((wm * 64 + lo) * 32) + kof) << 1);
  const unsigned bByte = ldsBase + 16384u + (unsigned)((((wn * 64 + lo) * 32) + kof) << 1);

  const int nT = K >> 5;
  STAGE(0, 0);
  for (int kt = 0; kt < nT; ++kt) {
    const int buf = kt & 1;
    if (kt + 1 < nT) {
      STAGE(kt + 1, buf ^ 1);
      asm volatile("s_waitcnt vmcnt(3)" ::: "memory");
    } else {
      asm volatile("s_waitcnt vmcnt(0)" ::: "memory");
    }
    __builtin_amdgcn_s_barrier();

    const unsigned aA = aByte + (unsigned)(buf << 13);
    const unsigned bA = bByte + (unsigned)(buf << 14);
    bf16x8 af0, af1, af2, af3, bf0, bf1, bf2, bf3;
    DSR(af0, aA, "0");    DSR(af1, aA, "1024");
    DSR(af2, aA, "2048"); DSR(af3, aA, "3072");
    DSR(bf0, bA, "0");    DSR(bf1, bA, "1024");
    DSR(bf2, bA, "2048"); DSR(bf3, bA, "3072");
    asm volatile("s_waitcnt lgkmcnt(0)" ::: "memory");
    __builtin_amdgcn_sched_barrier(0);
    __builtin_amdgcn_s_setprio(1);
#define MM(MI, NI) \
    acc[MI][NI] = __builtin_amdgcn_mfma_f32_16x16x32_bf16(af##MI, bf##NI, acc[MI][NI], 0, 0, 0)
    MM(0, 0); MM(0, 1); MM(0, 2); MM(0, 3);
    MM(1, 0); MM(1, 1); MM(1, 2); MM(1, 3);
    MM(2, 0); MM(2, 1); MM(2, 2); MM(2, 3);
    MM(3, 0); MM(3, 1); MM(3, 2); MM(3, 3);
#undef MM
    __builtin_amdgcn_s_setprio(0);
    __builtin_amdgcn_sched_barrier(0);
    __builtin_amdgcn_s_barrier();
  }
#undef STAGE

#pragma unroll
  for (int mi = 0; mi < 4; ++mi)
#pragma unroll
    for (int ni = 0; ni < 4; ++ni)
      store_frag<MODE>(acc[mi][ni], bias, Cout,
                       n0 + wn * 64 + ni * 16 + lo,
                       m0 + wm * 64 + mi * 16 + hi * 4);
}

// ---------------- chunked linear scan (vectorized: 4 ch/thread, chunk=64) ----------------
// ACT cols: [0,1024)=a_f  [1024,2048)=g_f  [2048,3072)=a_b  [3072,4096)=g_b

__global__ __launch_bounds__(256) void scan1v_kernel(const unsigned short* __restrict__ ACT,
                                                     float* __restrict__ CHA,
                                                     float* __restrict__ CHB) {
  int chunk = blockIdx.x & 63;
  int b = (blockIdx.x >> 6) & 3;
  int dir = blockIdx.x >> 8;
  int c4 = threadIdx.x * 4;
  size_t colA = (size_t)dir * 2048 + c4;
  float Ap[4] = {1.f, 1.f, 1.f, 1.f};
  float Bv[4] = {0.f, 0.f, 0.f, 0.f};
  int t0 = chunk * 64;
  for (int i = 0; i < 64; ++i) {
    int t = t0 + i;
    int s = dir ? (SEQ - 1 - t) : t;
    size_t base = ((size_t)b * SEQ + s) * 4096 + colA;
    u16x4 av = *(const u16x4*)&ACT[base];
    u16x4 gv = *(const u16x4*)&ACT[base + 1024];
#pragma unroll
    for (int j = 0; j < 4; ++j) {
      float a = bf2f(av[j]), g = bf2f(gv[j]);
      Bv[j] = a * Bv[j] + (1.f - a) * g;
      Ap[j] *= a;
    }
  }
  size_t o = ((size_t)(dir * 4 + b) * 64 + chunk) * 1024 + c4;
  *(float4*)&CHA[o] = (float4){Ap[0], Ap[1], Ap[2], Ap[3]};
  *(float4*)&CHB[o] = (float4){Bv[0], Bv[1], Bv[2], Bv[3]};
}

__global__ __launch_bounds__(256) void scan_phase2_kernel(const float* __restrict__ CHA,
                                                          const float* __restrict__ CHB,
                                                          float* __restrict__ HINIT) {
  int idx = blockIdx.x * 256 + threadIdx.x;  // 8192 = (dir*4+b)*1024 + c
  int c = idx & 1023;
  int db = idx >> 10;
  float h = 0.f;
  for (int ck = 0; ck < 64; ++ck) {
    size_t o = ((size_t)db * 64 + ck) * 1024 + c;
    HINIT[o] = h;
    h = CHA[o] * h + CHB[o];
  }
}

__global__ __launch_bounds__(256) void scan3v_kernel(const unsigned short* __restrict__ ACT,
                                                     const float* __restrict__ HINIT,
                                                     unsigned short* __restrict__ HCAT) {
  int chunk = blockIdx.x & 63;
  int b = (blockIdx.x >> 6) & 3;
  int dir = blockIdx.x >> 8;
  int c4 = threadIdx.x * 4;
  size_t colA = (size_t)dir * 2048 + c4;
  float4 h0 = *(const float4*)&HINIT[((size_t)(dir * 4 + b) * 64 + chunk) * 1024 + c4];
  float h[4] = {h0.x, h0.y, h0.z, h0.w};
  int t0 = chunk * 64;
  for (int i = 0; i < 64; ++i) {
    int t = t0 + i;
    int s = dir ? (SEQ - 1 - t) : t;
    size_t base = ((size_t)b * SEQ + s) * 4096 + colA;
    u16x4 av = *(const u16x4*)&ACT[base];
    u16x4 gv = *(const u16x4*)&ACT[base + 1024];
    u16x4 out;
#pragma unroll
    for (int j = 0; j < 4; ++j) {
      float a = bf2f(av[j]), g = bf2f(gv[j]);
      h[j] = a * h[j] + (1.f - a) * g;
      out[j] = f2bf(h[j]);
    }
    *(u16x4*)&HCAT[((size_t)b * SEQ + t) * 2048 + dir * 1024 + c4] = out;
  }
}

// ---------------- launcher ----------------

extern "C" void kernel_launch(void* const* d_in, const int* in_sizes, int n_in,
                              void* d_out, int out_size, void* d_ws, size_t ws_size,
                              hipStream_t stream) {
  (void)in_sizes; (void)n_in; (void)out_size; (void)ws_size;
  const float* x     = (const float*)d_in[0];
  const float* Wz_f  = (const float*)d_in[1];
  const float* bz_f  = (const float*)d_in[2];
  const float* Wh_f  = (const float*)d_in[3];
  const float* bh_f  = (const float*)d_in[4];
  const float* Wz_b  = (const float*)d_in[5];
  const float* bz_b  = (const float*)d_in[6];
  const float* Wh_b  = (const float*)d_in[7];
  const float* bh_b  = (const float*)d_in[8];
  const float* W_out = (const float*)d_in[9];
  const float* b_out = (const float*)d_in[10];

  char* ws = (char*)d_ws;
  size_t off = 0;
  auto alloc = [&](size_t bytes) {
    char* p = ws + off;
    off = (off + bytes + 255) & ~(size_t)255;
    return p;
  };
  const size_t M = 16384;  // B*S
  unsigned short* WT4   = (unsigned short*)alloc(4096ull * 1024 * 2);
  unsigned short* WTout = (unsigned short*)alloc(1024ull * 2048 * 2);
  unsigned short* ACT   = (unsigned short*)alloc(M * 4096 * 2);
  unsigned short* HCAT  = (unsigned short*)alloc(M * 2048 * 2);
  float* CHA   = (float*)alloc(524288ull * 4);
  float* CHB   = (float*)alloc(524288ull * 4);
  float* HINIT = (float*)alloc(524288ull * 4);
  float* b4    = (float*)alloc(4096 * 4);

  tconvb_kernel<<<dim3(32, 32, 6), 256, 0, stream>>>(Wz_f, Wh_f, Wz_b, Wh_b, W_out, WT4, WTout);
  concat_bias_kernel<<<16, 256, 0, stream>>>(bz_f, bh_f, bz_b, bh_b, b4);

  // GEMM1: M=16384, N=4096, K=1024 -> 256x256 tiles, 1024 blocks.
  // Reads x fp32 directly; converts to bf16 in-reg during staging (no cvt_x pass).
  gemm256x_kernel<<<1024, 512, 0, stream>>>(x, WT4, b4, (void*)ACT, 1024, 16);

  scan1v_kernel<<<512, 256, 0, stream>>>(ACT, CHA, CHB);
  scan_phase2_kernel<<<32, 256, 0, stream>>>(CHA, CHB, HINIT);
  scan3v_kernel<<<512, 256, 0, stream>>>(ACT, HINIT, HCAT);

  // GEMM2: M=16384, N=1024, K=2048 -> 128x256 tiles, 512 blocks (GLL)
  gemm128_kernel<1><<<512, 512, 0, stream>>>(HCAT, WTout, b_out, d_out, 2048, 4);
}

// Round 13
// 329.611 us; speedup vs baseline: 1.3652x; 1.3652x over previous
//
#include <hip/hip_runtime.h>
#include <stdint.h>

typedef __attribute__((ext_vector_type(8))) short bf16x8;
typedef __attribute__((ext_vector_type(4))) float f32x4;
typedef __attribute__((ext_vector_type(4))) unsigned short u16x4;

#define SEQ 4096

__device__ __forceinline__ float bf2f(unsigned short u) {
  union { unsigned int i; float f; } v; v.i = ((unsigned int)u) << 16; return v.f;
}
__device__ __forceinline__ unsigned short f2bf(float f) {
  union { float f; unsigned int i; } v; v.f = f;
  unsigned int u = v.i;
  u = u + 0x7FFFu + ((u >> 16) & 1u);
  return (unsigned short)(u >> 16);
}
__device__ __forceinline__ float sigm(float x) { return 1.0f / (1.0f + __expf(-x)); }

// ---------------- conversion kernels ----------------

__global__ void cvt_x_kernel(const float* __restrict__ in, unsigned short* __restrict__ out, int n8) {
  int i = blockIdx.x * blockDim.x + threadIdx.x;
  int stride = gridDim.x * blockDim.x;
  for (; i < n8; i += stride) {
    const float4* p = (const float4*)in + (size_t)i * 2;
    float4 a = p[0], b = p[1];
    union { unsigned short u[8]; uint4 v; } r;
    r.u[0] = f2bf(a.x); r.u[1] = f2bf(a.y); r.u[2] = f2bf(a.z); r.u[3] = f2bf(a.w);
    r.u[4] = f2bf(b.x); r.u[5] = f2bf(b.y); r.u[6] = f2bf(b.z); r.u[7] = f2bf(b.w);
    ((uint4*)out)[i] = r.v;
  }
}

// batched transpose fp32 [K][N] -> bf16 [N][K]; z selects matrix
__global__ void tconvb_kernel(const float* __restrict__ s0, const float* __restrict__ s1,
                              const float* __restrict__ s2, const float* __restrict__ s3,
                              const float* __restrict__ s4, unsigned short* __restrict__ WT4,
                              unsigned short* __restrict__ WTout) {
  __shared__ float t[32][33];
  int z = blockIdx.z;
  const float* src; unsigned short* dst; int K, k0;
  if (z < 4) {
    src = (z == 0) ? s0 : (z == 1) ? s1 : (z == 2) ? s2 : s3;
    dst = WT4 + (size_t)z * 1048576; K = 1024; k0 = blockIdx.y * 32;
  } else {
    src = s4; dst = WTout; K = 2048; k0 = blockIdx.y * 32 + (z - 4) * 1024;
  }
  int n0 = blockIdx.x * 32;
  int tx = threadIdx.x & 31, ty = threadIdx.x >> 5;
#pragma unroll
  for (int i = 0; i < 32; i += 8)
    t[ty + i][tx] = src[(size_t)(k0 + ty + i) * 1024 + n0 + tx];
  __syncthreads();
#pragma unroll
  for (int i = 0; i < 32; i += 8)
    dst[(size_t)(n0 + ty + i) * K + k0 + tx] = f2bf(t[tx][ty + i]);
}

__global__ void concat_bias_kernel(const float* b0, const float* b1, const float* b2,
                                   const float* b3, float* b4) {
  int i = blockIdx.x * 256 + threadIdx.x;  // 0..4095
  const float* p = (i < 1024) ? b0 : (i < 2048) ? b1 : (i < 3072) ? b2 : b3;
  b4[i] = p[i & 1023];
}

// ---------------- shared epilogue ----------------
template <int MODE>
__device__ __forceinline__ void store_frag(const f32x4& v, const float* bias, void* Cout,
                                           int col, int rb) {
  float bcol = bias[col];
  if (MODE == 0) {
    unsigned short* ACTp = (unsigned short*)Cout;
    bool isz = ((col >> 10) & 1) == 0;  // groups 0,2 are z-gates
#pragma unroll
    for (int r = 0; r < 4; ++r) {
      float x = v[r] + bcol;
      float res;
      if (isz) res = sigm(-x);                       // a = 1 - z
      else res = (x >= 0.f) ? (x + 0.5f) : sigm(x);  // g(x)
      ACTp[(size_t)(rb + r) * 4096 + col] = f2bf(res);
    }
  } else {
    float* Op = (float*)Cout;
#pragma unroll
    for (int r = 0; r < 4; ++r) Op[(size_t)(rb + r) * 1024 + col] = v[r] + bcol;
  }
}

// inline-asm ds_read_b128 (pinned; not sinkable/splittable)
#define DSR(D, A, OFFSTR) \
  asm volatile("ds_read_b128 %0, %1 offset:" OFFSTR : "=&v"(D) : "v"(A))

#define GLL(SRC, DIDX)                                                                  \
  __builtin_amdgcn_global_load_lds((const __attribute__((address_space(1))) void*)(SRC), \
                                   (__attribute__((address_space(3))) void*)&lds[DIDX], \
                                   16, 0, 0)

// ---------------- 256x256 GEMM1, fine-phase, 3-buffer, counted vmcnt(6) ----------
// 2-tile staging lead: compute tile t from buf t%3 while tile t+2 streams into
// buf (t+2)%3. vmcnt(6) drains ONLY tile-t's 4 loads (2 tiles old). GLL issue
// split across the two MFMA phases. R12 bug fixed: half-tile regions are 4096
// USHORTS apart (8 waves x 1024B per GLL), not 2048 -- +2048 left half the
// tile unwritten -> NaN from uninitialized LDS.
__global__ __launch_bounds__(512, 2) void gemm256p_kernel(
    const unsigned short* __restrict__ A, const unsigned short* __restrict__ BT,
    const float* __restrict__ bias, void* __restrict__ Cout, int K, int NT) {
  // ushort idx: buf b at b*16384: A rows 0-255 at +0..8191, B rows at +8192..16383.
  // row = 64B; swizzle kbyte ^= ((row>>1)&3)<<4
  __shared__ unsigned short lds[49152];  // 96 KB, 3 buffers

  const int tid = threadIdx.x;
  const int lane = tid & 63;
  const int wv = tid >> 6;
  const int wm = wv >> 2;
  const int wn = wv & 3;
  const int lo = lane & 15, hi = lane >> 4;

  const int nwg = gridDim.x;
  const int bid = blockIdx.x;
  const int cpx = nwg >> 3;
  const int sw = (bid & 7) * cpx + (bid >> 3);
  const int mt = sw / NT, nt = sw - mt * NT;
  const int m0 = mt << 8, n0 = nt << 8;

  const int srow = tid >> 2;
  const int skb = (((tid & 3) ^ ((tid >> 3) & 3)) << 4);
  const unsigned short* pA0 = A + (size_t)(m0 + srow) * K + (skb >> 1);
  const unsigned short* pA1 = pA0 + (size_t)128 * K;
  const unsigned short* pB0 = BT + (size_t)(n0 + srow) * K + (skb >> 1);
  const unsigned short* pB1 = pB0 + (size_t)128 * K;
  const int dstBase = wv << 9;  // ushort idx; HW adds lane*16B

#define STAGE_A(KT, BUFO)                           \
  do {                                              \
    const int ko_ = (KT) << 5;                      \
    GLL(pA0 + ko_, (BUFO) + dstBase);               \
    GLL(pA1 + ko_, (BUFO) + 4096 + dstBase);        \
  } while (0)
#define STAGE_B(KT, BUFO)                           \
  do {                                              \
    const int ko_ = (KT) << 5;                      \
    GLL(pB0 + ko_, (BUFO) + 8192 + dstBase);        \
    GLL(pB1 + ko_, (BUFO) + 8192 + 4096 + dstBase); \
  } while (0)

  f32x4 acc[8][4];
#pragma unroll
  for (int i = 0; i < 8; ++i)
#pragma unroll
    for (int j = 0; j < 4; ++j) acc[i][j] = (f32x4){0.f, 0.f, 0.f, 0.f};

  // fragment byte addresses within a buffer (same swizzle involution as staging)
  const int swz = ((lo >> 1) & 3) << 4;
  const int kof = ((hi << 4) ^ swz) >> 1;  // ushort offset in 64B row
  const unsigned ldsBase = (unsigned)(unsigned long long)&lds[0];
  const unsigned aByte = ldsBase + (unsigned)((((wm * 128 + lo) * 32) + kof) << 1);
  const unsigned bByte = ldsBase + 16384u + (unsigned)((((wn * 64 + lo) * 32) + kof) << 1);

  const int nT = K >> 5;  // 32 (GEMM1)
  // prologue: stage tiles 0 and 1 fully (buf 0, buf 1)
  STAGE_A(0, 0); STAGE_B(0, 0);
  STAGE_A(1, 16384); STAGE_B(1, 16384);

  int bufo = 0;       // (t%3) * 16384 ushorts
  int sbufo = 32768;  // ((t+2)%3) * 16384
  for (int t = 0; t < nT; ++t) {
    // ---- phase 1 ----
    if (t + 2 < nT) {
      STAGE_A(t + 2, sbufo);
      asm volatile("s_waitcnt vmcnt(6)" ::: "memory");   // drain tile-t's 4 only
    } else if (t + 1 < nT) {
      asm volatile("s_waitcnt vmcnt(4)" ::: "memory");   // drain tile-t's 4
    } else {
      asm volatile("s_waitcnt vmcnt(0)" ::: "memory");
    }
    __builtin_amdgcn_s_barrier();  // publish buf t to all waves

    const unsigned aA = aByte + (unsigned)(bufo << 1);
    const unsigned bA = bByte + (unsigned)(bufo << 1);
    bf16x8 af0, af1, af2, af3, af4, af5, af6, af7, bf0, bf1, bf2, bf3;
    DSR(af0, aA, "0");    DSR(af1, aA, "1024");
    DSR(af2, aA, "2048"); DSR(af3, aA, "3072");
    DSR(af4, aA, "4096"); DSR(af5, aA, "5120");
    DSR(af6, aA, "6144"); DSR(af7, aA, "7168");
    DSR(bf0, bA, "0");    DSR(bf1, bA, "1024");
    DSR(bf2, bA, "2048"); DSR(bf3, bA, "3072");
    asm volatile("s_waitcnt lgkmcnt(0)" ::: "memory");
    __builtin_amdgcn_sched_barrier(0);  // rule #18
    __builtin_amdgcn_s_setprio(1);
#define MM(MI, NI) \
    acc[MI][NI] = __builtin_amdgcn_mfma_f32_16x16x32_bf16(af##MI, bf##NI, acc[MI][NI], 0, 0, 0)
    MM(0, 0); MM(0, 1); MM(1, 0); MM(1, 1);
    MM(2, 0); MM(2, 1); MM(3, 0); MM(3, 1);
    MM(4, 0); MM(4, 1); MM(5, 0); MM(5, 1);
    MM(6, 0); MM(6, 1); MM(7, 0); MM(7, 1);
    __builtin_amdgcn_s_setprio(0);
    __builtin_amdgcn_sched_barrier(0);

    // ---- phase 2 ----
    if (t + 2 < nT) STAGE_B(t + 2, sbufo);
    __builtin_amdgcn_s_setprio(1);
    MM(0, 2); MM(0, 3); MM(1, 2); MM(1, 3);
    MM(2, 2); MM(2, 3); MM(3, 2); MM(3, 3);
    MM(4, 2); MM(4, 3); MM(5, 2); MM(5, 3);
    MM(6, 2); MM(6, 3); MM(7, 2); MM(7, 3);
#undef MM
    __builtin_amdgcn_s_setprio(0);
    __builtin_amdgcn_sched_barrier(0);
    // all reads of buf t long done (lgkm0 above); gate: no wave may stage into
    // this buf (at t+3) until every wave passed here.
    __builtin_amdgcn_s_barrier();

    bufo += 16384;  if (bufo == 49152) bufo = 0;
    sbufo += 16384; if (sbufo == 49152) sbufo = 0;
  }

#pragma unroll
  for (int mi = 0; mi < 8; ++mi)
#pragma unroll
    for (int ni = 0; ni < 4; ++ni)
      store_frag<0>(acc[mi][ni], bias, Cout,
                    n0 + wn * 64 + ni * 16 + lo,
                    m0 + wm * 128 + mi * 16 + hi * 4);
}
#undef STAGE_A
#undef STAGE_B

// ---------------- 128x256 GEMM (GEMM2), GLL staging ----------
template <int MODE>
__global__ __launch_bounds__(512, 2) void gemm128_kernel(
    const unsigned short* __restrict__ A, const unsigned short* __restrict__ BT,
    const float* __restrict__ bias, void* __restrict__ Cout, int K, int NT) {
  __shared__ unsigned short lds[24576];  // 48 KB

  const int tid = threadIdx.x;
  const int lane = tid & 63;
  const int wv = tid >> 6;
  const int wm = wv >> 2;
  const int wn = wv & 3;
  const int lo = lane & 15, hi = lane >> 4;

  const int nwg = gridDim.x;
  const int bid = blockIdx.x;
  const int cpx = nwg >> 3;
  const int sw = (bid & 7) * cpx + (bid >> 3);
  const int mt = sw / NT, nt = sw - mt * NT;
  const int m0 = mt << 7, n0 = nt << 8;

  const int srow = tid >> 2;
  const int skb = (((tid & 3) ^ ((tid >> 3) & 3)) << 4);
  const unsigned short* pA0 = A + (size_t)(m0 + srow) * K + (skb >> 1);
  const unsigned short* pB0 = BT + (size_t)(n0 + srow) * K + (skb >> 1);
  const unsigned short* pB1 = pB0 + (size_t)128 * K;
  const int dstBase = wv << 9;

#define STAGE(KT, BUF)                                    \
  do {                                                    \
    const int ko_ = (KT) << 5;                            \
    GLL(pA0 + ko_, (BUF) * 4096 + dstBase);               \
    GLL(pB0 + ko_, 8192 + (BUF) * 8192 + dstBase);        \
    GLL(pB1 + ko_, 8192 + (BUF) * 8192 + 4096 + dstBase); \
  } while (0)

  f32x4 acc[4][4];
#pragma unroll
  for (int i = 0; i < 4; ++i)
#pragma unroll
    for (int j = 0; j < 4; ++j) acc[i][j] = (f32x4){0.f, 0.f, 0.f, 0.f};

  const int swz = ((lo >> 1) & 3) << 4;
  const int kof = ((hi << 4) ^ swz) >> 1;
  const unsigned ldsBase = (unsigned)(unsigned long long)&lds[0];
  const unsigned aByte = ldsBase + (unsigned)((((wm * 64 + lo) * 32) + kof) << 1);
  const unsigned bByte = ldsBase + 16384u + (unsigned)((((wn * 64 + lo) * 32) + kof) << 1);

  const int nT = K >> 5;
  STAGE(0, 0);
  for (int kt = 0; kt < nT; ++kt) {
    const int buf = kt & 1;
    if (kt + 1 < nT) {
      STAGE(kt + 1, buf ^ 1);
      asm volatile("s_waitcnt vmcnt(3)" ::: "memory");
    } else {
      asm volatile("s_waitcnt vmcnt(0)" ::: "memory");
    }
    __builtin_amdgcn_s_barrier();

    const unsigned aA = aByte + (unsigned)(buf << 13);
    const unsigned bA = bByte + (unsigned)(buf << 14);
    bf16x8 af0, af1, af2, af3, bf0, bf1, bf2, bf3;
    DSR(af0, aA, "0");    DSR(af1, aA, "1024");
    DSR(af2, aA, "2048"); DSR(af3, aA, "3072");
    DSR(bf0, bA, "0");    DSR(bf1, bA, "1024");
    DSR(bf2, bA, "2048"); DSR(bf3, bA, "3072");
    asm volatile("s_waitcnt lgkmcnt(0)" ::: "memory");
    __builtin_amdgcn_sched_barrier(0);
    __builtin_amdgcn_s_setprio(1);
#define MM(MI, NI) \
    acc[MI][NI] = __builtin_amdgcn_mfma_f32_16x16x32_bf16(af##MI, bf##NI, acc[MI][NI], 0, 0, 0)
    MM(0, 0); MM(0, 1); MM(0, 2); MM(0, 3);
    MM(1, 0); MM(1, 1); MM(1, 2); MM(1, 3);
    MM(2, 0); MM(2, 1); MM(2, 2); MM(2, 3);
    MM(3, 0); MM(3, 1); MM(3, 2); MM(3, 3);
#undef MM
    __builtin_amdgcn_s_setprio(0);
    __builtin_amdgcn_sched_barrier(0);
    __builtin_amdgcn_s_barrier();
  }
#undef STAGE

#pragma unroll
  for (int mi = 0; mi < 4; ++mi)
#pragma unroll
    for (int ni = 0; ni < 4; ++ni)
      store_frag<MODE>(acc[mi][ni], bias, Cout,
                       n0 + wn * 64 + ni * 16 + lo,
                       m0 + wm * 64 + mi * 16 + hi * 4);
}

// ---------------- chunked linear scan (vectorized: 4 ch/thread, chunk=64) ----------------
// ACT cols: [0,1024)=a_f  [1024,2048)=g_f  [2048,3072)=a_b  [3072,4096)=g_b

__global__ __launch_bounds__(256) void scan1v_kernel(const unsigned short* __restrict__ ACT,
                                                     float* __restrict__ CHA,
                                                     float* __restrict__ CHB) {
  int chunk = blockIdx.x & 63;
  int b = (blockIdx.x >> 6) & 3;
  int dir = blockIdx.x >> 8;
  int c4 = threadIdx.x * 4;
  size_t colA = (size_t)dir * 2048 + c4;
  float Ap[4] = {1.f, 1.f, 1.f, 1.f};
  float Bv[4] = {0.f, 0.f, 0.f, 0.f};
  int t0 = chunk * 64;
  for (int i = 0; i < 64; ++i) {
    int t = t0 + i;
    int s = dir ? (SEQ - 1 - t) : t;
    size_t base = ((size_t)b * SEQ + s) * 4096 + colA;
    u16x4 av = *(const u16x4*)&ACT[base];
    u16x4 gv = *(const u16x4*)&ACT[base + 1024];
#pragma unroll
    for (int j = 0; j < 4; ++j) {
      float a = bf2f(av[j]), g = bf2f(gv[j]);
      Bv[j] = a * Bv[j] + (1.f - a) * g;
      Ap[j] *= a;
    }
  }
  size_t o = ((size_t)(dir * 4 + b) * 64 + chunk) * 1024 + c4;
  *(float4*)&CHA[o] = (float4){Ap[0], Ap[1], Ap[2], Ap[3]};
  *(float4*)&CHB[o] = (float4){Bv[0], Bv[1], Bv[2], Bv[3]};
}

__global__ __launch_bounds__(256) void scan_phase2_kernel(const float* __restrict__ CHA,
                                                          const float* __restrict__ CHB,
                                                          float* __restrict__ HINIT) {
  int idx = blockIdx.x * 256 + threadIdx.x;  // 8192 = (dir*4+b)*1024 + c
  int c = idx & 1023;
  int db = idx >> 10;
  float h = 0.f;
  for (int ck = 0; ck < 64; ++ck) {
    size_t o = ((size_t)db * 64 + ck) * 1024 + c;
    HINIT[o] = h;
    h = CHA[o] * h + CHB[o];
  }
}

__global__ __launch_bounds__(256) void scan3v_kernel(const unsigned short* __restrict__ ACT,
                                                     const float* __restrict__ HINIT,
                                                     unsigned short* __restrict__ HCAT) {
  int chunk = blockIdx.x & 63;
  int b = (blockIdx.x >> 6) & 3;
  int dir = blockIdx.x >> 8;
  int c4 = threadIdx.x * 4;
  size_t colA = (size_t)dir * 2048 + c4;
  float4 h0 = *(const float4*)&HINIT[((size_t)(dir * 4 + b) * 64 + chunk) * 1024 + c4];
  float h[4] = {h0.x, h0.y, h0.z, h0.w};
  int t0 = chunk * 64;
  for (int i = 0; i < 64; ++i) {
    int t = t0 + i;
    int s = dir ? (SEQ - 1 - t) : t;
    size_t base = ((size_t)b * SEQ + s) * 4096 + colA;
    u16x4 av = *(const u16x4*)&ACT[base];
    u16x4 gv = *(const u16x4*)&ACT[base + 1024];
    u16x4 out;
#pragma unroll
    for (int j = 0; j < 4; ++j) {
      float a = bf2f(av[j]), g = bf2f(gv[j]);
      h[j] = a * h[j] + (1.f - a) * g;
      out[j] = f2bf(h[j]);
    }
    *(u16x4*)&HCAT[((size_t)b * SEQ + t) * 2048 + dir * 1024 + c4] = out;
  }
}

// ---------------- launcher ----------------

extern "C" void kernel_launch(void* const* d_in, const int* in_sizes, int n_in,
                              void* d_out, int out_size, void* d_ws, size_t ws_size,
                              hipStream_t stream) {
  (void)in_sizes; (void)n_in; (void)out_size; (void)ws_size;
  const float* x     = (const float*)d_in[0];
  const float* Wz_f  = (const float*)d_in[1];
  const float* bz_f  = (const float*)d_in[2];
  const float* Wh_f  = (const float*)d_in[3];
  const float* bh_f  = (const float*)d_in[4];
  const float* Wz_b  = (const float*)d_in[5];
  const float* bz_b  = (const float*)d_in[6];
  const float* Wh_b  = (const float*)d_in[7];
  const float* bh_b  = (const float*)d_in[8];
  const float* W_out = (const float*)d_in[9];
  const float* b_out = (const float*)d_in[10];

  char* ws = (char*)d_ws;
  size_t off = 0;
  auto alloc = [&](size_t bytes) {
    char* p = ws + off;
    off = (off + bytes + 255) & ~(size_t)255;
    return p;
  };
  const size_t M = 16384;  // B*S
  unsigned short* xb    = (unsigned short*)alloc(M * 1024 * 2);
  unsigned short* WT4   = (unsigned short*)alloc(4096ull * 1024 * 2);
  unsigned short* WTout = (unsigned short*)alloc(1024ull * 2048 * 2);
  unsigned short* ACT   = (unsigned short*)alloc(M * 4096 * 2);
  unsigned short* HCAT  = (unsigned short*)alloc(M * 2048 * 2);
  float* CHA   = (float*)alloc(524288ull * 4);
  float* CHB   = (float*)alloc(524288ull * 4);
  float* HINIT = (float*)alloc(524288ull * 4);
  float* b4    = (float*)alloc(4096 * 4);

  cvt_x_kernel<<<2048, 256, 0, stream>>>(x, xb, (int)(M * 1024 / 8));

  tconvb_kernel<<<dim3(32, 32, 6), 256, 0, stream>>>(Wz_f, Wh_f, Wz_b, Wh_b, W_out, WT4, WTout);
  concat_bias_kernel<<<16, 256, 0, stream>>>(bz_f, bh_f, bz_b, bh_b, b4);

  // GEMM1: M=16384, N=4096, K=1024 -> 256x256 tiles, 1024 blocks (fine-phase)
  gemm256p_kernel<<<1024, 512, 0, stream>>>(xb, WT4, b4, (void*)ACT, 1024, 16);

  scan1v_kernel<<<512, 256, 0, stream>>>(ACT, CHA, CHB);
  scan_phase2_kernel<<<32, 256, 0, stream>>>(CHA, CHB, HINIT);
  scan3v_kernel<<<512, 256, 0, stream>>>(ACT, HINIT, HCAT);

  // GEMM2: M=16384, N=1024, K=2048 -> 128x256 tiles, 512 blocks
  gemm128_kernel<1><<<512, 512, 0, stream>>>(HCAT, WTout, b_out, d_out, 2048, 4);
}